// Round 1
// baseline (1556.670 us; speedup 1.0000x reference)
//
#include <hip/hip_runtime.h>

// Q8Linear: out[t][o] = (sum_k x[t][k]*w[o][k]) * xs[t] * ws[o] + bias[o]
// T=8192, K=4096, O=16384. Exact int32 accumulation via mfma_i32_16x16x64_i8.
//
// Phase 1: pack int32-valued int8 inputs to real int8 in d_ws (needs 96 MiB).
// Phase 2: 128x128-tile i8 MFMA GEMM (m97 structure: global_load_lds w=16,
//          BK=64, 4 waves x 4x4 16x16 tiles, fused dequant epilogue).

#define T_DIM 8192
#define K_DIM 4096
#define N_DIM 16384

typedef __attribute__((ext_vector_type(4))) int int4v;

__global__ __launch_bounds__(256) void pack_i8(const int4v* __restrict__ src,
                                               int* __restrict__ dst) {
  const int idx = blockIdx.x * 256 + threadIdx.x;
  int4v v = src[idx];
  dst[idx] = (v.x & 255) | ((v.y & 255) << 8) | ((v.z & 255) << 16) | (v.w << 24);
}

__global__ __launch_bounds__(256) void gemm_i8(
    const char* __restrict__ A8,        // [T_DIM][K_DIM] int8
    const char* __restrict__ B8,        // [N_DIM][K_DIM] int8 (o-major, K contiguous)
    const float* __restrict__ xscale,   // [T_DIM]
    const float* __restrict__ wscale,   // [N_DIM]
    const float* __restrict__ bias,     // [N_DIM]
    float* __restrict__ out) {          // [T_DIM][N_DIM] fp32
  __shared__ __align__(16) char lA[128 * 64];
  __shared__ __align__(16) char lB[128 * 64];

  const int tid = threadIdx.x;
  const int wave = tid >> 6;
  const int lane = tid & 63;
  const int blockM = blockIdx.y * 128;
  const int blockN = blockIdx.x * 128;
  const int waveM = (wave >> 1) * 64;   // 2x2 waves over the 128x128 tile
  const int waveN = (wave & 1) * 64;

  int4v acc[4][4] = {};                 // 4x4 tiles of 16x16, int32x4 each

  // Staging: thread tid loads 16B from global row (tid>>2), col 16*(tid&3).
  // global_load_lds lands lane l's 16B at (wave-uniform base) + l*16, which
  // is exactly row-major [row][col] for this assignment — no padding allowed.
  const int srow = tid >> 2;            // 0..63
  const int scol = (tid & 3) << 4;      // 0,16,32,48
  const char* ag = A8 + (size_t)(blockM + srow) * K_DIM + scol;
  const char* bg = B8 + (size_t)(blockN + srow) * K_DIM + scol;
  char* lAdst = lA + wave * 1024;       // wave-uniform LDS base
  char* lBdst = lB + wave * 1024;

  // Fragment read addresses (A[m][k]: m=lane&15, k=q*16+j; B[k][n]: n=lane&15)
  const int q = lane >> 4;
  const int arow = waveM + (lane & 15);
  const int brow = waveN + (lane & 15);

  for (int k0 = 0; k0 < K_DIM; k0 += 64) {
    __syncthreads();  // previous iter's ds_reads done before overwrite
    __builtin_amdgcn_global_load_lds(
        (const __attribute__((address_space(1))) void*)(ag + k0),
        (__attribute__((address_space(3))) void*)(lAdst), 16, 0, 0);
    __builtin_amdgcn_global_load_lds(
        (const __attribute__((address_space(1))) void*)(ag + k0 + (size_t)64 * K_DIM),
        (__attribute__((address_space(3))) void*)(lAdst + 4096), 16, 0, 0);
    __builtin_amdgcn_global_load_lds(
        (const __attribute__((address_space(1))) void*)(bg + k0),
        (__attribute__((address_space(3))) void*)(lBdst), 16, 0, 0);
    __builtin_amdgcn_global_load_lds(
        (const __attribute__((address_space(1))) void*)(bg + k0 + (size_t)64 * K_DIM),
        (__attribute__((address_space(3))) void*)(lBdst + 4096), 16, 0, 0);
    __syncthreads();  // compiler emits s_waitcnt vmcnt(0) before s_barrier

    int4v afrag[4], bfrag[4];
#pragma unroll
    for (int i = 0; i < 4; ++i) {
      afrag[i] = *(const int4v*)(lA + ((arow + i * 16) * 64 + q * 16));
      bfrag[i] = *(const int4v*)(lB + ((brow + i * 16) * 64 + q * 16));
    }
#pragma unroll
    for (int im = 0; im < 4; ++im)
#pragma unroll
      for (int in = 0; in < 4; ++in)
        acc[im][in] = __builtin_amdgcn_mfma_i32_16x16x64_i8(
            afrag[im], bfrag[in], acc[im][in], 0, 0, 0);
  }

  // Epilogue: C/D layout col=lane&15, row=q*4+reg (dtype-independent, m121-128)
  const int row0 = blockM + waveM + q * 4;
  const int col0 = blockN + waveN + (lane & 15);
#pragma unroll
  for (int in = 0; in < 4; ++in) {
    const int o = col0 + in * 16;
    const float so = wscale[o];
    const float bo = bias[o];
#pragma unroll
    for (int im = 0; im < 4; ++im) {
      const int t = row0 + im * 16;
#pragma unroll
      for (int r = 0; r < 4; ++r) {
        const float v = (float)acc[im][in][r] * xscale[t + r] * so + bo;
        out[(size_t)(t + r) * N_DIM + o] = v;
      }
    }
  }
}

extern "C" void kernel_launch(void* const* d_in, const int* in_sizes, int n_in,
                              void* d_out, int out_size, void* d_ws, size_t ws_size,
                              hipStream_t stream) {
  const int* x = (const int*)d_in[0];       // [T_DIM][K_DIM] int32 (int8-valued)
  const int* w = (const int*)d_in[1];       // [N_DIM][K_DIM] int32 (int8-valued)
  const float* bias = (const float*)d_in[2];
  const float* xs = (const float*)d_in[3];
  const float* ws = (const float*)d_in[4];
  float* out = (float*)d_out;

  char* x8 = (char*)d_ws;                           // 32 MiB
  char* w8 = x8 + (size_t)T_DIM * K_DIM;            // 64 MiB

  pack_i8<<<(T_DIM * K_DIM) / 1024, 256, 0, stream>>>((const int4v*)x, (int*)x8);
  pack_i8<<<(N_DIM / 4) * (K_DIM / 256), 256, 0, stream>>>((const int4v*)w, (int*)w8);

  dim3 grid(N_DIM / 128, T_DIM / 128);   // 128 x 64 = 8192 blocks
  gemm_i8<<<grid, 256, 0, stream>>>(x8, w8, xs, ws, bias, out);
}